// Round 1
// baseline (2345.919 us; speedup 1.0000x reference)
//
#include <hip/hip_runtime.h>

#define NN 10000
#define EE 160000
#define FF 128
#define LL 8
#define BB 64
#define DD 512
#define ND (NN * DD)

typedef unsigned short u16;
typedef __attribute__((ext_vector_type(8))) short short8;
typedef __attribute__((ext_vector_type(8))) __bf16 bf16x8;
typedef __attribute__((ext_vector_type(4))) float f32x4;
typedef __attribute__((ext_vector_type(4))) u16 u16x4;

__device__ __forceinline__ u16 f2bf(float f) {
  unsigned u = __float_as_uint(f);
  return (u16)((u + 0x7FFFu + ((u >> 16) & 1u)) >> 16);
}
__device__ __forceinline__ float bf2f(u16 h) {
  return __uint_as_float(((unsigned)h) << 16);
}

// ---------------- split fp32 -> bf16 hi/lo ----------------
__global__ void k_split(const float* __restrict__ in, u16* __restrict__ hi,
                        u16* __restrict__ lo, int n4) {
  int i = blockIdx.x * 256 + threadIdx.x;
  if (i >= n4) return;
  float4 v = ((const float4*)in)[i];
  u16x4 h, l;
  h.x = f2bf(v.x); l.x = f2bf(v.x - bf2f(h.x));
  h.y = f2bf(v.y); l.y = f2bf(v.y - bf2f(h.y));
  h.z = f2bf(v.z); l.z = f2bf(v.z - bf2f(h.z));
  h.w = f2bf(v.w); l.w = f2bf(v.w - bf2f(h.w));
  ((u16x4*)hi)[i] = h;
  ((u16x4*)lo)[i] = l;
}

// ---------------- weight transpose+convert: W[K][512] -> Wt[4][512][K] hi/lo ----------------
__global__ void k_convw(const float* __restrict__ W0, const float* __restrict__ W1,
                        const float* __restrict__ W2, const float* __restrict__ W3,
                        int K, u16* __restrict__ whi, u16* __restrict__ wlo) {
  __shared__ float t[32][33];
  int mat = blockIdx.z;
  const float* W = (mat == 0) ? W0 : (mat == 1) ? W1 : (mat == 2) ? W2 : W3;
  int n0 = blockIdx.x * 32, k0 = blockIdx.y * 32;
  int tx = threadIdx.x, ty = threadIdx.y;
#pragma unroll
  for (int i = 0; i < 4; ++i)
    t[ty + 8 * i][tx] = W[(k0 + ty + 8 * i) * 512 + n0 + tx];
  __syncthreads();
#pragma unroll
  for (int i = 0; i < 4; ++i) {
    int n = n0 + ty + 8 * i;
    float val = t[tx][ty + 8 * i];
    u16 hi = f2bf(val);
    u16 lo = f2bf(val - bf2f(hi));
    int o = (mat * 512 + n) * K + k0 + tx;
    whi[o] = hi;
    wlo[o] = lo;
  }
}

__global__ void k_fbias(const float* __restrict__ b0, const float* __restrict__ b1,
                        const float* __restrict__ b2, const float* __restrict__ b3,
                        float* __restrict__ biasf) {
  int j = blockIdx.x * 256 + threadIdx.x;
  if (j < 2048) {
    int m = j >> 9;
    const float* p = (m == 0) ? b0 : (m == 1) ? b1 : (m == 2) ? b2 : b3;
    biasf[j] = p[j & 511];
  }
}

// ---------------- fused q|k|v|s GEMM: [M,K] x [K,2048] via bf16 hi/lo split ----------------
__global__ __launch_bounds__(256) void k_gemm(
    const u16* __restrict__ Ahg, const u16* __restrict__ Alg,
    const u16* __restrict__ Bhg, const u16* __restrict__ Blg,
    const float* __restrict__ biasf,
    float* __restrict__ oq, float* __restrict__ okk,
    float* __restrict__ ov, float* __restrict__ os,
    int M, int K) {
  __shared__ short8 sAh[512], sAl[512], sBh[512], sBl[512];
  const int tid = threadIdx.x;
  const int jt = blockIdx.x, mt = blockIdx.y;
  const int m0 = mt * 128;
  const int mat = jt >> 2;
  const int nbase = (jt & 3) * 128;
  const int K8 = K >> 3;
  const int l = tid & 63, wv = tid >> 6;
  const int wr = wv >> 1, wc = wv & 1;
  const int g = l >> 4, li = l & 15;
  const int srow = tid >> 2, scg = tid & 3;

  const f32x4 zero4 = {0.f, 0.f, 0.f, 0.f};
  f32x4 acc[4][4];
#pragma unroll
  for (int i = 0; i < 4; ++i)
#pragma unroll
    for (int j = 0; j < 4; ++j) acc[i][j] = zero4;

  const short8* gAh = (const short8*)Ahg;
  const short8* gAl = (const short8*)Alg;
  const short8* gBh = (const short8*)Bhg;
  const short8* gBl = (const short8*)Blg;
  const short8 z8 = {0, 0, 0, 0, 0, 0, 0, 0};
  const int browbase = mat * 512 + nbase;

  for (int kg0 = 0; kg0 < K8; kg0 += 4) {
#pragma unroll
    for (int rr = 0; rr < 2; ++rr) {
      int r = srow + rr * 64;
      int gm = m0 + r;
      short8 vh = z8, vl = z8;
      if (gm < M) {
        int gi = gm * K8 + kg0 + scg;
        vh = gAh[gi];
        vl = gAl[gi];
      }
      int sidx = r * 4 + (scg ^ (r & 3));
      sAh[sidx] = vh;
      sAl[sidx] = vl;
      int gib = (browbase + r) * K8 + kg0 + scg;
      sBh[sidx] = gBh[gib];
      sBl[sidx] = gBl[gib];
    }
    __syncthreads();
    bf16x8 fah[4], fal[4], fbh[4], fbl[4];
#pragma unroll
    for (int mi = 0; mi < 4; ++mi) {
      int ml = wr * 64 + mi * 16 + li;
      int idx = ml * 4 + (g ^ (ml & 3));
      fah[mi] = __builtin_bit_cast(bf16x8, sAh[idx]);
      fal[mi] = __builtin_bit_cast(bf16x8, sAl[idx]);
    }
#pragma unroll
    for (int ni = 0; ni < 4; ++ni) {
      int nl = wc * 64 + ni * 16 + li;
      int idx = nl * 4 + (g ^ (nl & 3));
      fbh[ni] = __builtin_bit_cast(bf16x8, sBh[idx]);
      fbl[ni] = __builtin_bit_cast(bf16x8, sBl[idx]);
    }
#pragma unroll
    for (int mi = 0; mi < 4; ++mi)
#pragma unroll
      for (int ni = 0; ni < 4; ++ni) {
        acc[mi][ni] = __builtin_amdgcn_mfma_f32_16x16x32_bf16(fah[mi], fbh[ni], acc[mi][ni], 0, 0, 0);
        acc[mi][ni] = __builtin_amdgcn_mfma_f32_16x16x32_bf16(fah[mi], fbl[ni], acc[mi][ni], 0, 0, 0);
        acc[mi][ni] = __builtin_amdgcn_mfma_f32_16x16x32_bf16(fal[mi], fbh[ni], acc[mi][ni], 0, 0, 0);
      }
    __syncthreads();
  }

  float* outp = (mat == 0) ? oq : (mat == 1) ? okk : (mat == 2) ? ov : os;
#pragma unroll
  for (int mi = 0; mi < 4; ++mi)
#pragma unroll
    for (int ni = 0; ni < 4; ++ni) {
      int col = nbase + wc * 64 + ni * 16 + li;
      float bv = biasf[(jt << 7) + wc * 64 + ni * 16 + li];
      int rbase = m0 + wr * 64 + mi * 16 + g * 4;
#pragma unroll
      for (int r = 0; r < 4; ++r) {
        int gm = rbase + r;
        if (gm < M) outp[gm * 512 + col] = acc[mi][ni][r] + bv;
      }
    }
}

// ---------------- CSR build ----------------
__global__ void k_count(const int* __restrict__ dst, int* __restrict__ counts) {
  int e = blockIdx.x * 256 + threadIdx.x;
  if (e < EE) atomicAdd(&counts[dst[e]], 1);
}

__global__ void k_scan(const int* __restrict__ counts, int* __restrict__ offs) {
  __shared__ int s[1024];
  __shared__ int carry;
  int tid = threadIdx.x;
  if (tid == 0) { carry = 0; offs[0] = 0; }
  __syncthreads();
  for (int c0 = 0; c0 < NN; c0 += 1024) {
    int i = c0 + tid;
    int val = (i < NN) ? counts[i] : 0;
    s[tid] = val;
    __syncthreads();
    for (int d = 1; d < 1024; d <<= 1) {
      int t = (tid >= d) ? s[tid - d] : 0;
      __syncthreads();
      s[tid] += t;
      __syncthreads();
    }
    if (i < NN) offs[i + 1] = carry + s[tid];
    __syncthreads();
    if (tid == 1023) carry += s[1023];
    __syncthreads();
  }
}

__global__ void k_scatter(const int* __restrict__ src, const int* __restrict__ dst,
                          const int* __restrict__ offs, int* __restrict__ cursor,
                          int* __restrict__ esrc) {
  int e = blockIdx.x * 256 + threadIdx.x;
  if (e < EE) {
    int d = dst[e];
    int pos = offs[d] + atomicAdd(&cursor[d], 1);
    esrc[pos] = src[e];
  }
}

__global__ void k_bstart(const int* __restrict__ batch, int* __restrict__ bstart) {
  int n = blockIdx.x * 256 + threadIdx.x;
  if (n > NN) return;
  if (n == 0) {
    for (int b = 0; b <= batch[0]; ++b) bstart[b] = 0;
  } else if (n == NN) {
    for (int b = batch[NN - 1] + 1; b <= BB; ++b) bstart[b] = NN;
  } else {
    int bp = batch[n - 1], bn = batch[n];
    for (int b = bp + 1; b <= bn; ++b) bstart[b] = n;
  }
}

// ---------------- per-node flash attention over incoming edges ----------------
__global__ __launch_bounds__(256) void k_attn(
    const float* __restrict__ q, const float* __restrict__ k, const float* __restrict__ v,
    float* __restrict__ s, const int* __restrict__ offs, const int* __restrict__ esrc) {
  int node = blockIdx.x * 4 + (threadIdx.x >> 6);
  int l = threadIdx.x & 63;
  const float4* qp = (const float4*)(q + node * 512);
  float4 q0 = qp[l * 2], q1 = qp[l * 2 + 1];
  float m = -__builtin_inff(), ssum = 0.f;
  float a0 = 0, a1 = 0, a2 = 0, a3 = 0, a4 = 0, a5 = 0, a6 = 0, a7 = 0;
  int e0 = offs[node], e1 = offs[node + 1];
  for (int e = e0; e < e1; ++e) {
    int sn = esrc[e];
    const float4* kp = (const float4*)(k + sn * 512);
    float4 k0 = kp[l * 2], k1 = kp[l * 2 + 1];
    float d = q0.x * k0.x + q0.y * k0.y + q0.z * k0.z + q0.w * k0.w +
              q1.x * k1.x + q1.y * k1.y + q1.z * k1.z + q1.w * k1.w;
    d += __shfl_xor(d, 1);
    d += __shfl_xor(d, 2);
    d += __shfl_xor(d, 4);
    float logit = d * 0.125f;
    float mn = fmaxf(m, logit);
    float sc = __expf(m - mn);
    float p = __expf(logit - mn);
    const float4* vp = (const float4*)(v + sn * 512);
    float4 v0 = vp[l * 2], v1 = vp[l * 2 + 1];
    ssum = ssum * sc + p;
    a0 = a0 * sc + p * v0.x; a1 = a1 * sc + p * v0.y;
    a2 = a2 * sc + p * v0.z; a3 = a3 * sc + p * v0.w;
    a4 = a4 * sc + p * v1.x; a5 = a5 * sc + p * v1.y;
    a6 = a6 * sc + p * v1.z; a7 = a7 * sc + p * v1.w;
    m = mn;
  }
  float inv = (e1 > e0) ? 1.f / (ssum + 1e-16f) : 0.f;
  float4* sp = (float4*)(s + node * 512);
  float4 s0 = sp[l * 2], s1 = sp[l * 2 + 1];
  s0.x += a0 * inv; s0.y += a1 * inv; s0.z += a2 * inv; s0.w += a3 * inv;
  s1.x += a4 * inv; s1.y += a5 * inv; s1.z += a6 * inv; s1.w += a7 * inv;
  sp[l * 2] = s0;
  sp[l * 2 + 1] = s1;
}

// ---------------- BatchNorm ----------------
__global__ void k_bnstat(const float* __restrict__ s, float* __restrict__ acc) {
  int c = blockIdx.x * 256 + threadIdx.x;
  float sum = 0.f, sq = 0.f;
  for (int r = blockIdx.y; r < NN; r += 64) {
    float x = s[r * 512 + c];
    sum += x;
    sq += x * x;
  }
  atomicAdd(&acc[c], sum);
  atomicAdd(&acc[512 + c], sq);
}

__global__ void k_bnfinal(const float* __restrict__ acc, const float* __restrict__ gamma,
                          const float* __restrict__ beta, float* __restrict__ scale,
                          float* __restrict__ shift) {
  int c = threadIdx.x;
  float mu = acc[c] * (1.f / NN);
  float var = acc[512 + c] * (1.f / NN) - mu * mu;
  float inv = rsqrtf(var + 1e-5f);
  float scl = gamma[c] * inv;
  scale[c] = scl;
  shift[c] = beta[c] - mu * scl;
}

__global__ void k_bnapply(const float* __restrict__ s, const float* __restrict__ scale,
                          const float* __restrict__ shift, float* __restrict__ h,
                          u16* __restrict__ hhi, u16* __restrict__ hlo) {
  int i = blockIdx.x * 256 + threadIdx.x;  // group of 4 elements
  float4 val = ((const float4*)s)[i];
  int c4 = i & 127;
  float4 scl = ((const float4*)scale)[c4];
  float4 shf = ((const float4*)shift)[c4];
  float4 r;
  r.x = fmaxf(val.x * scl.x + shf.x, 0.f);
  r.y = fmaxf(val.y * scl.y + shf.y, 0.f);
  r.z = fmaxf(val.z * scl.z + shf.z, 0.f);
  r.w = fmaxf(val.w * scl.w + shf.w, 0.f);
  ((float4*)h)[i] = r;
  u16x4 hv, lv;
  hv.x = f2bf(r.x); lv.x = f2bf(r.x - bf2f(hv.x));
  hv.y = f2bf(r.y); lv.y = f2bf(r.y - bf2f(hv.y));
  hv.z = f2bf(r.z); lv.z = f2bf(r.z - bf2f(hv.z));
  hv.w = f2bf(r.w); lv.w = f2bf(r.w - bf2f(hv.w));
  ((u16x4*)hhi)[i] = hv;
  ((u16x4*)hlo)[i] = lv;
}

__global__ void k_pool(const float* __restrict__ h, const int* __restrict__ bstart,
                       float* __restrict__ out, int layer) {
  int c = blockIdx.x * 256 + threadIdx.x;
  int b = blockIdx.y;
  int r0 = bstart[b], r1 = bstart[b + 1];
  float sum = 0.f;
  for (int r = r0; r < r1; ++r) sum += h[r * 512 + c];
  out[b * 4096 + layer * 512 + c] = sum / fmaxf((float)(r1 - r0), 1.f);
}

// ---------------- host ----------------
extern "C" void kernel_launch(void* const* d_in, const int* in_sizes, int n_in,
                              void* d_out, int out_size, void* d_ws, size_t ws_size,
                              hipStream_t stream) {
  (void)in_sizes; (void)n_in; (void)out_size; (void)ws_size;
  const float* x = (const float*)d_in[0];
  const int* ei = (const int*)d_in[1];
  const int* src = ei;
  const int* dst = ei + EE;
  const int* batch = (const int*)d_in[2];
  const float* W0q = (const float*)d_in[3];
  const float* b0q = (const float*)d_in[4];
  const float* W0k = (const float*)d_in[5];
  const float* b0k = (const float*)d_in[6];
  const float* W0v = (const float*)d_in[7];
  const float* b0v = (const float*)d_in[8];
  const float* W0s = (const float*)d_in[9];
  const float* b0s = (const float*)d_in[10];
  const float* Wq = (const float*)d_in[11];
  const float* bq = (const float*)d_in[12];
  const float* Wk = (const float*)d_in[13];
  const float* bk = (const float*)d_in[14];
  const float* Wv = (const float*)d_in[15];
  const float* bv = (const float*)d_in[16];
  const float* Ws = (const float*)d_in[17];
  const float* bs = (const float*)d_in[18];
  const float* gamma = (const float*)d_in[19];
  const float* beta = (const float*)d_in[20];
  float* out = (float*)d_out;

  char* w = (char*)d_ws;
  size_t off = 0;
  auto alloc = [&](size_t bytes) -> void* {
    void* p = w + off;
    off = (off + bytes + 255) & ~(size_t)255;
    return p;
  };
  float* h = (float*)alloc((size_t)ND * 4);
  u16* hhi = (u16*)alloc((size_t)ND * 2);
  u16* hlo = (u16*)alloc((size_t)ND * 2);
  float* qb = (float*)alloc((size_t)ND * 4);
  float* kb = (float*)alloc((size_t)ND * 4);
  float* vb = (float*)alloc((size_t)ND * 4);
  float* sb = (float*)alloc((size_t)ND * 4);
  u16* wthi = (u16*)alloc((size_t)4 * 512 * 512 * 2);
  u16* wtlo = (u16*)alloc((size_t)4 * 512 * 512 * 2);
  float* biasf = (float*)alloc(2048 * 4);
  float* bnacc = (float*)alloc(1024 * 4);
  float* bnscale = (float*)alloc(512 * 4);
  float* bnshift = (float*)alloc(512 * 4);
  int* counts = (int*)alloc(NN * 4);
  int* offs = (int*)alloc((NN + 1) * 4);
  int* cursor = (int*)alloc(NN * 4);
  int* esrc = (int*)alloc(EE * 4);
  int* bstart = (int*)alloc((BB + 1) * 4);

  // ---- CSR + batch boundaries (edges/batch constant across layers) ----
  hipMemsetAsync(counts, 0, NN * 4, stream);
  hipMemsetAsync(cursor, 0, NN * 4, stream);
  k_count<<<EE / 256, 256, 0, stream>>>(dst, counts);
  k_scan<<<1, 1024, 0, stream>>>(counts, offs);
  k_scatter<<<EE / 256, 256, 0, stream>>>(src, dst, offs, cursor, esrc);
  k_bstart<<<(NN + 256) / 256, 256, 0, stream>>>(batch, bstart);

  for (int layer = 0; layer < LL; ++layer) {
    int K = (layer == 0) ? FF : DD;
    if (layer == 0) {
      k_split<<<(NN * FF / 4) / 256, 256, 0, stream>>>(x, hhi, hlo, NN * FF / 4);
      k_convw<<<dim3(16, K / 32, 4), dim3(32, 8), 0, stream>>>(W0q, W0k, W0v, W0s, K, wthi, wtlo);
      k_fbias<<<8, 256, 0, stream>>>(b0q, b0k, b0v, b0s, biasf);
    } else {
      const float* wq = Wq + (size_t)(layer - 1) * DD * DD;
      const float* wk = Wk + (size_t)(layer - 1) * DD * DD;
      const float* wv = Wv + (size_t)(layer - 1) * DD * DD;
      const float* ws = Ws + (size_t)(layer - 1) * DD * DD;
      k_convw<<<dim3(16, K / 32, 4), dim3(32, 8), 0, stream>>>(wq, wk, wv, ws, K, wthi, wtlo);
      k_fbias<<<8, 256, 0, stream>>>(bq + (layer - 1) * DD, bk + (layer - 1) * DD,
                                     bv + (layer - 1) * DD, bs + (layer - 1) * DD, biasf);
    }
    k_gemm<<<dim3(16, 79), 256, 0, stream>>>(hhi, hlo, wthi, wtlo, biasf, qb, kb, vb, sb, NN, K);
    k_attn<<<NN / 4, 256, 0, stream>>>(qb, kb, vb, sb, offs, esrc);
    hipMemsetAsync(bnacc, 0, 1024 * 4, stream);
    k_bnstat<<<dim3(2, 64), 256, 0, stream>>>(sb, bnacc);
    k_bnfinal<<<1, 512, 0, stream>>>(bnacc, gamma + layer * DD, beta + layer * DD, bnscale, bnshift);
    k_bnapply<<<(ND / 4) / 256, 256, 0, stream>>>(sb, bnscale, bnshift, h, hhi, hlo);
    k_pool<<<dim3(2, 64), 256, 0, stream>>>(h, bstart, out, layer);
  }
}

// Round 2
// 1879.147 us; speedup vs baseline: 1.2484x; 1.2484x over previous
//
#include <hip/hip_runtime.h>

#define NN 10000
#define EE 160000
#define FF 128
#define LL 8
#define BB 64
#define DD 512
#define ND (NN * DD)

typedef unsigned short u16;
typedef __attribute__((ext_vector_type(8))) short short8;
typedef __attribute__((ext_vector_type(8))) __bf16 bf16x8;
typedef __attribute__((ext_vector_type(4))) float f32x4;
typedef __attribute__((ext_vector_type(4))) u16 u16x4;

__device__ __forceinline__ u16 f2bf(float f) {
  unsigned u = __float_as_uint(f);
  return (u16)((u + 0x7FFFu + ((u >> 16) & 1u)) >> 16);
}
__device__ __forceinline__ float bf2f(u16 h) {
  return __uint_as_float(((unsigned)h) << 16);
}

#define GLOAD_LDS16(gp, lp)                                                   \
  __builtin_amdgcn_global_load_lds(                                           \
      (const __attribute__((address_space(1))) void*)(gp),                    \
      (__attribute__((address_space(3))) void*)(lp), 16, 0, 0)

// ---------------- split fp32 -> bf16 hi/lo ----------------
__global__ void k_split(const float* __restrict__ in, u16* __restrict__ hi,
                        u16* __restrict__ lo, int n4) {
  int i = blockIdx.x * 256 + threadIdx.x;
  if (i >= n4) return;
  float4 v = ((const float4*)in)[i];
  u16x4 h, l;
  h.x = f2bf(v.x); l.x = f2bf(v.x - bf2f(h.x));
  h.y = f2bf(v.y); l.y = f2bf(v.y - bf2f(h.y));
  h.z = f2bf(v.z); l.z = f2bf(v.z - bf2f(h.z));
  h.w = f2bf(v.w); l.w = f2bf(v.w - bf2f(h.w));
  ((u16x4*)hi)[i] = h;
  ((u16x4*)lo)[i] = l;
}

// ---------------- weight transpose+convert: W[K][512] -> Wt[4][512][K] (hi only) ----------------
__global__ void k_convw(const float* __restrict__ W0, const float* __restrict__ W1,
                        const float* __restrict__ W2, const float* __restrict__ W3,
                        int K, u16* __restrict__ whi) {
  __shared__ float t[32][33];
  int mat = blockIdx.z;
  const float* W = (mat == 0) ? W0 : (mat == 1) ? W1 : (mat == 2) ? W2 : W3;
  int n0 = blockIdx.x * 32, k0 = blockIdx.y * 32;
  int tx = threadIdx.x, ty = threadIdx.y;
#pragma unroll
  for (int i = 0; i < 4; ++i)
    t[ty + 8 * i][tx] = W[(k0 + ty + 8 * i) * 512 + n0 + tx];
  __syncthreads();
#pragma unroll
  for (int i = 0; i < 4; ++i) {
    int n = n0 + ty + 8 * i;
    float val = t[tx][ty + 8 * i];
    int o = (mat * 512 + n) * K + k0 + tx;
    whi[o] = f2bf(val);
  }
}

__global__ void k_fbias(const float* __restrict__ b0, const float* __restrict__ b1,
                        const float* __restrict__ b2, const float* __restrict__ b3,
                        float* __restrict__ biasf) {
  int j = blockIdx.x * 256 + threadIdx.x;
  if (j < 2048) {
    int m = j >> 9;
    const float* p = (m == 0) ? b0 : (m == 1) ? b1 : (m == 2) ? b2 : b3;
    biasf[j] = p[j & 511];
  }
}

// ---------------- fused q|k|v|s GEMM (m97 structure, 2-term hi/lo) ----------------
// A[M][K] bf16 hi/lo, B as Wt[2048][K] bf16 hi. C = Ah*Bh + Al*Bh.
// q,s outputs fp32; k,v outputs bf16 for the attention gather.
__global__ __launch_bounds__(256) void k_gemm(
    const u16* __restrict__ Ahg, const u16* __restrict__ Alg,
    const u16* __restrict__ Bhg, const float* __restrict__ biasf,
    float* __restrict__ oq, u16* __restrict__ ok16, u16* __restrict__ ov16,
    float* __restrict__ os, int M, int K) {
  __shared__ short8 sAh[512], sAl[512], sBh[512];
  const int tid = threadIdx.x;
  const int jt = blockIdx.x, mt = blockIdx.y;
  const int m0 = mt * 128;
  const int mat = jt >> 2;
  const int nbase = (jt & 3) * 128;
  const int K8 = K >> 3;
  const int l = tid & 63;
  const int wr = tid >> 7, wc = (tid >> 6) & 1;
  const int g = l >> 4, li = l & 15;

  // staging map: LDS chunk c holds global chunk (r=c>>2, (c&3)^(r&3))
  const int c0 = tid, c1 = tid + 256;
  const int r0 = c0 >> 2, r1 = c1 >> 2;
  const int j0 = (c0 & 3) ^ (r0 & 3), j1 = (c1 & 3) ^ (r1 & 3);
  const int am0 = min(m0 + r0, M - 1), am1 = min(m0 + r1, M - 1);
  const int brow = mat * 512 + nbase;
  const short8* gAh = (const short8*)Ahg;
  const short8* gAl = (const short8*)Alg;
  const short8* gBh = (const short8*)Bhg;
  const size_t a0 = (size_t)am0 * K8 + j0, a1 = (size_t)am1 * K8 + j1;
  const size_t b0 = (size_t)(brow + r0) * K8 + j0, b1 = (size_t)(brow + r1) * K8 + j1;

  const f32x4 zero4 = {0.f, 0.f, 0.f, 0.f};
  f32x4 acc[4][4];
#pragma unroll
  for (int i = 0; i < 4; ++i)
#pragma unroll
    for (int j = 0; j < 4; ++j) acc[i][j] = zero4;

  for (int kg = 0; kg < K8; kg += 4) {
    GLOAD_LDS16(gAh + a0 + kg, &sAh[c0]);
    GLOAD_LDS16(gAh + a1 + kg, &sAh[c1]);
    GLOAD_LDS16(gAl + a0 + kg, &sAl[c0]);
    GLOAD_LDS16(gAl + a1 + kg, &sAl[c1]);
    GLOAD_LDS16(gBh + b0 + kg, &sBh[c0]);
    GLOAD_LDS16(gBh + b1 + kg, &sBh[c1]);
    __syncthreads();  // compiler drains vmcnt before barrier
    bf16x8 fah[4], fal[4], fbh[4];
#pragma unroll
    for (int mi = 0; mi < 4; ++mi) {
      int row = wr * 64 + mi * 16 + li;
      int idx = row * 4 + (g ^ (row & 3));
      fah[mi] = __builtin_bit_cast(bf16x8, sAh[idx]);
      fal[mi] = __builtin_bit_cast(bf16x8, sAl[idx]);
    }
#pragma unroll
    for (int ni = 0; ni < 4; ++ni) {
      int row = wc * 64 + ni * 16 + li;
      int idx = row * 4 + (g ^ (row & 3));
      fbh[ni] = __builtin_bit_cast(bf16x8, sBh[idx]);
    }
#pragma unroll
    for (int mi = 0; mi < 4; ++mi)
#pragma unroll
      for (int ni = 0; ni < 4; ++ni) {
        acc[mi][ni] = __builtin_amdgcn_mfma_f32_16x16x32_bf16(fah[mi], fbh[ni], acc[mi][ni], 0, 0, 0);
        acc[mi][ni] = __builtin_amdgcn_mfma_f32_16x16x32_bf16(fal[mi], fbh[ni], acc[mi][ni], 0, 0, 0);
      }
    __syncthreads();
  }

#pragma unroll
  for (int mi = 0; mi < 4; ++mi) {
    int rbase = m0 + wr * 64 + mi * 16 + g * 4;
#pragma unroll
    for (int ni = 0; ni < 4; ++ni) {
      int col = nbase + wc * 64 + ni * 16 + li;
      float bv = biasf[(jt << 7) + wc * 64 + ni * 16 + li];
#pragma unroll
      for (int r = 0; r < 4; ++r) {
        int gm = rbase + r;
        if (gm < M) {
          float val = acc[mi][ni][r] + bv;
          size_t o = (size_t)gm * 512 + col;
          if (mat == 0) oq[o] = val;
          else if (mat == 1) ok16[o] = f2bf(val);
          else if (mat == 2) ov16[o] = f2bf(val);
          else os[o] = val;
        }
      }
    }
  }
}

// ---------------- CSR build ----------------
__global__ void k_count(const int* __restrict__ dst, int* __restrict__ counts) {
  int e = blockIdx.x * 256 + threadIdx.x;
  if (e < EE) atomicAdd(&counts[dst[e]], 1);
}

__global__ void k_scan(const int* __restrict__ counts, int* __restrict__ offs) {
  __shared__ int s[1024];
  __shared__ int carry;
  int tid = threadIdx.x;
  if (tid == 0) { carry = 0; offs[0] = 0; }
  __syncthreads();
  for (int c0 = 0; c0 < NN; c0 += 1024) {
    int i = c0 + tid;
    int val = (i < NN) ? counts[i] : 0;
    s[tid] = val;
    __syncthreads();
    for (int d = 1; d < 1024; d <<= 1) {
      int t = (tid >= d) ? s[tid - d] : 0;
      __syncthreads();
      s[tid] += t;
      __syncthreads();
    }
    if (i < NN) offs[i + 1] = carry + s[tid];
    __syncthreads();
    if (tid == 1023) carry += s[1023];
    __syncthreads();
  }
}

__global__ void k_scatter(const int* __restrict__ src, const int* __restrict__ dst,
                          const int* __restrict__ offs, int* __restrict__ cursor,
                          int* __restrict__ esrc) {
  int e = blockIdx.x * 256 + threadIdx.x;
  if (e < EE) {
    int d = dst[e];
    int pos = offs[d] + atomicAdd(&cursor[d], 1);
    esrc[pos] = src[e];
  }
}

__global__ void k_bstart(const int* __restrict__ batch, int* __restrict__ bstart) {
  int n = blockIdx.x * 256 + threadIdx.x;
  if (n > NN) return;
  if (n == 0) {
    for (int b = 0; b <= batch[0]; ++b) bstart[b] = 0;
  } else if (n == NN) {
    for (int b = batch[NN - 1] + 1; b <= BB; ++b) bstart[b] = NN;
  } else {
    int bp = batch[n - 1], bn = batch[n];
    for (int b = bp + 1; b <= bn; ++b) bstart[b] = n;
  }
}

// ---------------- per-node flash attention (bf16 k/v, unroll-2) ----------------
__device__ __forceinline__ void bf8tof(short8 x, float* f) {
#pragma unroll
  for (int j = 0; j < 8; ++j) f[j] = bf2f((u16)x[j]);
}

__global__ __launch_bounds__(256) void k_attn(
    const float* __restrict__ q, const u16* __restrict__ k16,
    const u16* __restrict__ v16, float* __restrict__ s,
    const int* __restrict__ offs, const int* __restrict__ esrc) {
  int node = blockIdx.x * 4 + (threadIdx.x >> 6);
  int l = threadIdx.x & 63;
  const float4* qp = (const float4*)(q + (size_t)node * 512);
  float4 q0 = qp[l * 2], q1 = qp[l * 2 + 1];
  float qf[8] = {q0.x, q0.y, q0.z, q0.w, q1.x, q1.y, q1.z, q1.w};
  const short8* kp = (const short8*)k16;
  const short8* vp = (const short8*)v16;
  float m = -3.4e38f, ssum = 0.f;
  float a[8] = {0.f, 0.f, 0.f, 0.f, 0.f, 0.f, 0.f, 0.f};
  int e0 = offs[node], e1 = offs[node + 1];
  int e = e0;
  for (; e + 2 <= e1; e += 2) {
    int sn0 = esrc[e], sn1 = esrc[e + 1];
    short8 kk0 = kp[(size_t)sn0 * 64 + l];
    short8 kk1 = kp[(size_t)sn1 * 64 + l];
    short8 vv0 = vp[(size_t)sn0 * 64 + l];
    short8 vv1 = vp[(size_t)sn1 * 64 + l];
    float kf0[8], kf1[8];
    bf8tof(kk0, kf0);
    bf8tof(kk1, kf1);
    float d0 = 0.f, d1 = 0.f;
#pragma unroll
    for (int j = 0; j < 8; ++j) { d0 += qf[j] * kf0[j]; d1 += qf[j] * kf1[j]; }
    d0 += __shfl_xor(d0, 1); d1 += __shfl_xor(d1, 1);
    d0 += __shfl_xor(d0, 2); d1 += __shfl_xor(d1, 2);
    d0 += __shfl_xor(d0, 4); d1 += __shfl_xor(d1, 4);
    float vf0[8], vf1[8];
    bf8tof(vv0, vf0);
    bf8tof(vv1, vf1);
    {
      float logit = d0 * 0.125f;
      float mn = fmaxf(m, logit);
      float sc = __expf(m - mn), p = __expf(logit - mn);
      ssum = ssum * sc + p;
#pragma unroll
      for (int j = 0; j < 8; ++j) a[j] = a[j] * sc + p * vf0[j];
      m = mn;
    }
    {
      float logit = d1 * 0.125f;
      float mn = fmaxf(m, logit);
      float sc = __expf(m - mn), p = __expf(logit - mn);
      ssum = ssum * sc + p;
#pragma unroll
      for (int j = 0; j < 8; ++j) a[j] = a[j] * sc + p * vf1[j];
      m = mn;
    }
  }
  if (e < e1) {
    int sn0 = esrc[e];
    short8 kk0 = kp[(size_t)sn0 * 64 + l];
    short8 vv0 = vp[(size_t)sn0 * 64 + l];
    float kf0[8], vf0[8];
    bf8tof(kk0, kf0);
    bf8tof(vv0, vf0);
    float d0 = 0.f;
#pragma unroll
    for (int j = 0; j < 8; ++j) d0 += qf[j] * kf0[j];
    d0 += __shfl_xor(d0, 1);
    d0 += __shfl_xor(d0, 2);
    d0 += __shfl_xor(d0, 4);
    float logit = d0 * 0.125f;
    float mn = fmaxf(m, logit);
    float sc = __expf(m - mn), p = __expf(logit - mn);
    ssum = ssum * sc + p;
#pragma unroll
    for (int j = 0; j < 8; ++j) a[j] = a[j] * sc + p * vf0[j];
    m = mn;
  }
  float inv = (e1 > e0) ? 1.f / (ssum + 1e-16f) : 0.f;
  float4* sp = (float4*)(s + (size_t)node * 512);
  float4 s0 = sp[l * 2], s1 = sp[l * 2 + 1];
  s0.x += a[0] * inv; s0.y += a[1] * inv; s0.z += a[2] * inv; s0.w += a[3] * inv;
  s1.x += a[4] * inv; s1.y += a[5] * inv; s1.z += a[6] * inv; s1.w += a[7] * inv;
  sp[l * 2] = s0;
  sp[l * 2 + 1] = s1;
}

// ---------------- BatchNorm ----------------
__global__ void k_bnstat(const float* __restrict__ s, float* __restrict__ acc) {
  int c = blockIdx.x * 256 + threadIdx.x;
  float sum = 0.f, sq = 0.f;
  for (int r = blockIdx.y; r < NN; r += 64) {
    float x = s[(size_t)r * 512 + c];
    sum += x;
    sq += x * x;
  }
  atomicAdd(&acc[c], sum);
  atomicAdd(&acc[512 + c], sq);
}

__global__ void k_bnfinal(const float* __restrict__ acc, const float* __restrict__ gamma,
                          const float* __restrict__ beta, float* __restrict__ scale,
                          float* __restrict__ shift) {
  int c = threadIdx.x;
  float mu = acc[c] * (1.f / NN);
  float var = acc[512 + c] * (1.f / NN) - mu * mu;
  float inv = rsqrtf(var + 1e-5f);
  float scl = gamma[c] * inv;
  scale[c] = scl;
  shift[c] = beta[c] - mu * scl;
}

// BN+ReLU, write next-layer bf16 hi/lo activations only (no fp32 h)
__global__ void k_bnapply(const float* __restrict__ s, const float* __restrict__ scale,
                          const float* __restrict__ shift,
                          u16* __restrict__ hhi, u16* __restrict__ hlo) {
  int i = blockIdx.x * 256 + threadIdx.x;  // group of 4 elements
  float4 val = ((const float4*)s)[i];
  int c4 = i & 127;
  float4 scl = ((const float4*)scale)[c4];
  float4 shf = ((const float4*)shift)[c4];
  float4 r;
  r.x = fmaxf(val.x * scl.x + shf.x, 0.f);
  r.y = fmaxf(val.y * scl.y + shf.y, 0.f);
  r.z = fmaxf(val.z * scl.z + shf.z, 0.f);
  r.w = fmaxf(val.w * scl.w + shf.w, 0.f);
  u16x4 hv, lv;
  hv.x = f2bf(r.x); lv.x = f2bf(r.x - bf2f(hv.x));
  hv.y = f2bf(r.y); lv.y = f2bf(r.y - bf2f(hv.y));
  hv.z = f2bf(r.z); lv.z = f2bf(r.z - bf2f(hv.z));
  hv.w = f2bf(r.w); lv.w = f2bf(r.w - bf2f(hv.w));
  ((u16x4*)hhi)[i] = hv;
  ((u16x4*)hlo)[i] = lv;
}

// pool applies BN+ReLU on the fly from s (saves the fp32 h round-trip)
__global__ void k_pool(const float* __restrict__ s, const float* __restrict__ scale,
                       const float* __restrict__ shift, const int* __restrict__ bstart,
                       float* __restrict__ out, int layer) {
  int c = blockIdx.x * 256 + threadIdx.x;
  int b = blockIdx.y;
  int r0 = bstart[b], r1 = bstart[b + 1];
  float scl = scale[c], shf = shift[c];
  float sum = 0.f;
  for (int r = r0; r < r1; ++r)
    sum += fmaxf(s[(size_t)r * 512 + c] * scl + shf, 0.f);
  out[b * 4096 + layer * 512 + c] = sum / fmaxf((float)(r1 - r0), 1.f);
}

// ---------------- host ----------------
extern "C" void kernel_launch(void* const* d_in, const int* in_sizes, int n_in,
                              void* d_out, int out_size, void* d_ws, size_t ws_size,
                              hipStream_t stream) {
  (void)in_sizes; (void)n_in; (void)out_size; (void)ws_size;
  const float* x = (const float*)d_in[0];
  const int* ei = (const int*)d_in[1];
  const int* src = ei;
  const int* dst = ei + EE;
  const int* batch = (const int*)d_in[2];
  const float* W0q = (const float*)d_in[3];
  const float* b0q = (const float*)d_in[4];
  const float* W0k = (const float*)d_in[5];
  const float* b0k = (const float*)d_in[6];
  const float* W0v = (const float*)d_in[7];
  const float* b0v = (const float*)d_in[8];
  const float* W0s = (const float*)d_in[9];
  const float* b0s = (const float*)d_in[10];
  const float* Wq = (const float*)d_in[11];
  const float* bq = (const float*)d_in[12];
  const float* Wk = (const float*)d_in[13];
  const float* bk = (const float*)d_in[14];
  const float* Wv = (const float*)d_in[15];
  const float* bv = (const float*)d_in[16];
  const float* Ws = (const float*)d_in[17];
  const float* bs = (const float*)d_in[18];
  const float* gamma = (const float*)d_in[19];
  const float* beta = (const float*)d_in[20];
  float* out = (float*)d_out;

  char* w = (char*)d_ws;
  size_t off = 0;
  auto alloc = [&](size_t bytes) -> void* {
    void* p = w + off;
    off = (off + bytes + 255) & ~(size_t)255;
    return p;
  };
  u16* hhi = (u16*)alloc((size_t)ND * 2);
  u16* hlo = (u16*)alloc((size_t)ND * 2);
  float* qb = (float*)alloc((size_t)ND * 4);
  u16* kb16 = (u16*)alloc((size_t)ND * 2);
  u16* vb16 = (u16*)alloc((size_t)ND * 2);
  float* sb = (float*)alloc((size_t)ND * 4);
  u16* wthi = (u16*)alloc((size_t)4 * 512 * 512 * 2);
  float* biasf = (float*)alloc(2048 * 4);
  float* bnacc = (float*)alloc(1024 * 4);
  float* bnscale = (float*)alloc(512 * 4);
  float* bnshift = (float*)alloc(512 * 4);
  int* counts = (int*)alloc(NN * 4);
  int* offs = (int*)alloc((NN + 1) * 4);
  int* cursor = (int*)alloc(NN * 4);
  int* esrc = (int*)alloc(EE * 4);
  int* bstart = (int*)alloc((BB + 1) * 4);

  // ---- CSR + batch boundaries (constant across layers) ----
  hipMemsetAsync(counts, 0, NN * 4, stream);
  hipMemsetAsync(cursor, 0, NN * 4, stream);
  k_count<<<EE / 256, 256, 0, stream>>>(dst, counts);
  k_scan<<<1, 1024, 0, stream>>>(counts, offs);
  k_scatter<<<EE / 256, 256, 0, stream>>>(src, dst, offs, cursor, esrc);
  k_bstart<<<(NN + 256) / 256, 256, 0, stream>>>(batch, bstart);

  for (int layer = 0; layer < LL; ++layer) {
    int K = (layer == 0) ? FF : DD;
    if (layer == 0) {
      k_split<<<(NN * FF / 4) / 256, 256, 0, stream>>>(x, hhi, hlo, NN * FF / 4);
      k_convw<<<dim3(16, K / 32, 4), dim3(32, 8), 0, stream>>>(W0q, W0k, W0v, W0s, K, wthi);
      k_fbias<<<8, 256, 0, stream>>>(b0q, b0k, b0v, b0s, biasf);
    } else {
      const float* wq = Wq + (size_t)(layer - 1) * DD * DD;
      const float* wk = Wk + (size_t)(layer - 1) * DD * DD;
      const float* wv = Wv + (size_t)(layer - 1) * DD * DD;
      const float* ws = Ws + (size_t)(layer - 1) * DD * DD;
      k_convw<<<dim3(16, K / 32, 4), dim3(32, 8), 0, stream>>>(wq, wk, wv, ws, K, wthi);
      k_fbias<<<8, 256, 0, stream>>>(bq + (layer - 1) * DD, bk + (layer - 1) * DD,
                                     bv + (layer - 1) * DD, bs + (layer - 1) * DD, biasf);
    }
    k_gemm<<<dim3(16, 79), 256, 0, stream>>>(hhi, hlo, wthi, biasf, qb, kb16, vb16, sb, NN, K);
    k_attn<<<NN / 4, 256, 0, stream>>>(qb, kb16, vb16, sb, offs, esrc);
    hipMemsetAsync(bnacc, 0, 1024 * 4, stream);
    k_bnstat<<<dim3(2, 64), 256, 0, stream>>>(sb, bnacc);
    k_bnfinal<<<1, 512, 0, stream>>>(bnacc, gamma + layer * DD, beta + layer * DD, bnscale, bnshift);
    k_bnapply<<<(ND / 4) / 256, 256, 0, stream>>>(sb, bnscale, bnshift, hhi, hlo);
    k_pool<<<dim3(2, 64), 256, 0, stream>>>(sb, bnscale, bnshift, bstart, out, layer);
  }
}

// Round 4
// 1743.798 us; speedup vs baseline: 1.3453x; 1.0776x over previous
//
#include <hip/hip_runtime.h>

#define NN 10000
#define EE 160000
#define FF 128
#define LL 8
#define BB 64
#define DD 512
#define ND (NN * DD)

typedef unsigned short u16;
typedef __attribute__((ext_vector_type(8))) short short8;
typedef __attribute__((ext_vector_type(8))) _Float16 f16x8;
typedef __attribute__((ext_vector_type(4))) float f32x4;
typedef __attribute__((ext_vector_type(4))) u16 u16x4;

__device__ __forceinline__ u16 f2h(float f) {
  return __builtin_bit_cast(u16, (_Float16)f);
}

#define GLOAD_LDS16(gp, lp)                                                   \
  __builtin_amdgcn_global_load_lds(                                           \
      (const __attribute__((address_space(1))) void*)(gp),                    \
      (__attribute__((address_space(3))) void*)(lp), 16, 0, 0)

// ---------------- fp32 -> fp16 ----------------
__global__ void k_toh(const float* __restrict__ in, u16* __restrict__ out, int n4) {
  int i = blockIdx.x * 256 + threadIdx.x;
  if (i >= n4) return;
  float4 v = ((const float4*)in)[i];
  u16x4 h;
  h.x = f2h(v.x); h.y = f2h(v.y); h.z = f2h(v.z); h.w = f2h(v.w);
  ((u16x4*)out)[i] = h;
}

// ---------------- weight transpose+convert: W[lay][K][512] -> out[(lay*2048+mat*512+n)*K+k] fp16 ----------------
__global__ void k_convw(const float* __restrict__ W0, const float* __restrict__ W1,
                        const float* __restrict__ W2, const float* __restrict__ W3,
                        int K, u16* __restrict__ out) {
  __shared__ float t[32][33];
  int z = blockIdx.z;
  int lay = z >> 2, mat = z & 3;
  const float* W = ((mat == 0) ? W0 : (mat == 1) ? W1 : (mat == 2) ? W2 : W3) +
                   (size_t)lay * K * 512;
  int n0 = blockIdx.x * 32, k0 = blockIdx.y * 32;
  int tx = threadIdx.x, ty = threadIdx.y;
#pragma unroll
  for (int i = 0; i < 4; ++i)
    t[ty + 8 * i][tx] = W[(size_t)(k0 + ty + 8 * i) * 512 + n0 + tx];
  __syncthreads();
#pragma unroll
  for (int i = 0; i < 4; ++i) {
    int n = n0 + ty + 8 * i;
    float val = t[tx][ty + 8 * i];
    size_t o = ((size_t)lay * 2048 + mat * 512 + n) * K + k0 + tx;
    out[o] = f2h(val);
  }
}

// all-layer bias gather: biasf[l][2048]
__global__ void k_fbias(const float* __restrict__ b0q, const float* __restrict__ b0k,
                        const float* __restrict__ b0v, const float* __restrict__ b0s,
                        const float* __restrict__ bq, const float* __restrict__ bk,
                        const float* __restrict__ bv, const float* __restrict__ bs,
                        float* __restrict__ biasf) {
  int j = blockIdx.x * 256 + threadIdx.x;  // 0..16383
  int l = j >> 11, m = (j >> 9) & 3, c = j & 511;
  const float* p;
  if (l == 0) {
    p = (m == 0) ? b0q : (m == 1) ? b0k : (m == 2) ? b0v : b0s;
  } else {
    const float* base = (m == 0) ? bq : (m == 1) ? bk : (m == 2) ? bv : bs;
    p = base + (size_t)(l - 1) * 512;
  }
  biasf[j] = p[c];
}

// ---------------- fused q|k|v|s GEMM (m97 structure, fp16 single-term) ----------------
__global__ __launch_bounds__(256) void k_gemm(
    const u16* __restrict__ Ag, const u16* __restrict__ Bg,
    const float* __restrict__ biasf,
    float* __restrict__ oq, u16* __restrict__ ok16, u16* __restrict__ ov16,
    float* __restrict__ os, int M, int K) {
  __shared__ short8 sA[512], sB[512];
  const int tid = threadIdx.x;
  const int jt = blockIdx.x, mt = blockIdx.y;
  const int m0 = mt * 128;
  const int mat = jt >> 2;
  const int nbase = (jt & 3) * 128;
  const int K8 = K >> 3;
  const int l = tid & 63;
  const int wr = tid >> 7, wc = (tid >> 6) & 1;
  const int g = l >> 4, li = l & 15;

  // staging: LDS chunk c (row r=c>>2, slot jl=c&3) holds global chunk jl ^ s(r),
  // s(r) = (r&3) ^ ((r>>2)&3)  -- spreads rows {0,4,8,12} across bank groups
  const int c0 = tid, c1 = tid + 256;
  const int r0 = c0 >> 2, r1 = c1 >> 2;
  const int j0 = (c0 & 3) ^ (r0 & 3) ^ ((r0 >> 2) & 3);
  const int j1 = (c1 & 3) ^ (r1 & 3) ^ ((r1 >> 2) & 3);
  const int am0 = min(m0 + r0, M - 1), am1 = min(m0 + r1, M - 1);
  const int brow = mat * 512 + nbase;
  const short8* gA = (const short8*)Ag;
  const short8* gB = (const short8*)Bg;
  const size_t a0 = (size_t)am0 * K8 + j0, a1 = (size_t)am1 * K8 + j1;
  const size_t b0 = (size_t)(brow + r0) * K8 + j0, b1 = (size_t)(brow + r1) * K8 + j1;

  const f32x4 zero4 = {0.f, 0.f, 0.f, 0.f};
  f32x4 acc[4][4];
#pragma unroll
  for (int i = 0; i < 4; ++i)
#pragma unroll
    for (int j = 0; j < 4; ++j) acc[i][j] = zero4;

  for (int kg = 0; kg < K8; kg += 4) {
    GLOAD_LDS16(gA + a0 + kg, &sA[c0]);
    GLOAD_LDS16(gA + a1 + kg, &sA[c1]);
    GLOAD_LDS16(gB + b0 + kg, &sB[c0]);
    GLOAD_LDS16(gB + b1 + kg, &sB[c1]);
    __syncthreads();
    f16x8 fa[4], fb[4];
#pragma unroll
    for (int mi = 0; mi < 4; ++mi) {
      int row = wr * 64 + mi * 16 + li;
      int idx = row * 4 + (g ^ (row & 3) ^ ((row >> 2) & 3));
      fa[mi] = __builtin_bit_cast(f16x8, sA[idx]);
    }
#pragma unroll
    for (int ni = 0; ni < 4; ++ni) {
      int row = wc * 64 + ni * 16 + li;
      int idx = row * 4 + (g ^ (row & 3) ^ ((row >> 2) & 3));
      fb[ni] = __builtin_bit_cast(f16x8, sB[idx]);
    }
#pragma unroll
    for (int mi = 0; mi < 4; ++mi)
#pragma unroll
      for (int ni = 0; ni < 4; ++ni)
        acc[mi][ni] = __builtin_amdgcn_mfma_f32_16x16x32_f16(fa[mi], fb[ni], acc[mi][ni], 0, 0, 0);
    __syncthreads();
  }

#pragma unroll
  for (int mi = 0; mi < 4; ++mi) {
    int rbase = m0 + wr * 64 + mi * 16 + g * 4;
#pragma unroll
    for (int ni = 0; ni < 4; ++ni) {
      int col = nbase + wc * 64 + ni * 16 + li;
      float bv = biasf[(jt << 7) + wc * 64 + ni * 16 + li];
#pragma unroll
      for (int r = 0; r < 4; ++r) {
        int gm = rbase + r;
        if (gm < M) {
          float val = acc[mi][ni][r] + bv;
          size_t o = (size_t)gm * 512 + col;
          if (mat == 0) oq[o] = val;
          else if (mat == 1) ok16[o] = f2h(val);
          else if (mat == 2) ov16[o] = f2h(val);
          else os[o] = val;
        }
      }
    }
  }
}

// ---------------- CSR build ----------------
__global__ void k_count(const int* __restrict__ dst, int* __restrict__ counts) {
  int e = blockIdx.x * 256 + threadIdx.x;
  if (e < EE) atomicAdd(&counts[dst[e]], 1);
}

__global__ void k_scan(const int* __restrict__ counts, int* __restrict__ offs) {
  __shared__ int s[1024];
  __shared__ int carry;
  int tid = threadIdx.x;
  if (tid == 0) { carry = 0; offs[0] = 0; }
  __syncthreads();
  for (int c0 = 0; c0 < NN; c0 += 1024) {
    int i = c0 + tid;
    int val = (i < NN) ? counts[i] : 0;
    s[tid] = val;
    __syncthreads();
    for (int d = 1; d < 1024; d <<= 1) {
      int t = (tid >= d) ? s[tid - d] : 0;
      __syncthreads();
      s[tid] += t;
      __syncthreads();
    }
    if (i < NN) offs[i + 1] = carry + s[tid];
    __syncthreads();
    if (tid == 1023) carry += s[1023];
    __syncthreads();
  }
}

__global__ void k_scatter(const int* __restrict__ src, const int* __restrict__ dst,
                          const int* __restrict__ offs, int* __restrict__ cursor,
                          int* __restrict__ esrc) {
  int e = blockIdx.x * 256 + threadIdx.x;
  if (e < EE) {
    int d = dst[e];
    int pos = offs[d] + atomicAdd(&cursor[d], 1);
    esrc[pos] = src[e];
  }
}

__global__ void k_bstart(const int* __restrict__ batch, int* __restrict__ bstart) {
  int n = blockIdx.x * 256 + threadIdx.x;
  if (n > NN) return;
  if (n == 0) {
    for (int b = 0; b <= batch[0]; ++b) bstart[b] = 0;
  } else if (n == NN) {
    for (int b = batch[NN - 1] + 1; b <= BB; ++b) bstart[b] = NN;
  } else {
    int bp = batch[n - 1], bn = batch[n];
    for (int b = bp + 1; b <= bn; ++b) bstart[b] = n;
  }
}

// ---------------- per-node flash attention (fp16 k/v, unroll-2) ----------------
__device__ __forceinline__ void h8tof(short8 x, float* f) {
  f16x8 h = __builtin_bit_cast(f16x8, x);
#pragma unroll
  for (int j = 0; j < 8; ++j) f[j] = (float)h[j];
}

__global__ __launch_bounds__(256) void k_attn(
    const float* __restrict__ q, const u16* __restrict__ k16,
    const u16* __restrict__ v16, float* __restrict__ s,
    const int* __restrict__ offs, const int* __restrict__ esrc) {
  int node = blockIdx.x * 4 + (threadIdx.x >> 6);
  int l = threadIdx.x & 63;
  const float4* qp = (const float4*)(q + (size_t)node * 512);
  float4 q0 = qp[l * 2], q1 = qp[l * 2 + 1];
  float qf[8] = {q0.x, q0.y, q0.z, q0.w, q1.x, q1.y, q1.z, q1.w};
  const short8* kp = (const short8*)k16;
  const short8* vp = (const short8*)v16;
  float m = -3.4e38f, ssum = 0.f;
  float a[8] = {0.f, 0.f, 0.f, 0.f, 0.f, 0.f, 0.f, 0.f};
  int e0 = offs[node], e1 = offs[node + 1];
  int e = e0;
  for (; e + 2 <= e1; e += 2) {
    int sn0 = esrc[e], sn1 = esrc[e + 1];
    short8 kk0 = kp[(size_t)sn0 * 64 + l];
    short8 kk1 = kp[(size_t)sn1 * 64 + l];
    short8 vv0 = vp[(size_t)sn0 * 64 + l];
    short8 vv1 = vp[(size_t)sn1 * 64 + l];
    float kf0[8], kf1[8];
    h8tof(kk0, kf0);
    h8tof(kk1, kf1);
    float d0 = 0.f, d1 = 0.f;
#pragma unroll
    for (int j = 0; j < 8; ++j) { d0 += qf[j] * kf0[j]; d1 += qf[j] * kf1[j]; }
    d0 += __shfl_xor(d0, 1); d1 += __shfl_xor(d1, 1);
    d0 += __shfl_xor(d0, 2); d1 += __shfl_xor(d1, 2);
    d0 += __shfl_xor(d0, 4); d1 += __shfl_xor(d1, 4);
    float vf0[8], vf1[8];
    h8tof(vv0, vf0);
    h8tof(vv1, vf1);
    {
      float logit = d0 * 0.125f;
      float mn = fmaxf(m, logit);
      float sc = __expf(m - mn), p = __expf(logit - mn);
      ssum = ssum * sc + p;
#pragma unroll
      for (int j = 0; j < 8; ++j) a[j] = a[j] * sc + p * vf0[j];
      m = mn;
    }
    {
      float logit = d1 * 0.125f;
      float mn = fmaxf(m, logit);
      float sc = __expf(m - mn), p = __expf(logit - mn);
      ssum = ssum * sc + p;
#pragma unroll
      for (int j = 0; j < 8; ++j) a[j] = a[j] * sc + p * vf1[j];
      m = mn;
    }
  }
  if (e < e1) {
    int sn0 = esrc[e];
    short8 kk0 = kp[(size_t)sn0 * 64 + l];
    short8 vv0 = vp[(size_t)sn0 * 64 + l];
    float kf0[8], vf0[8];
    h8tof(kk0, kf0);
    h8tof(vv0, vf0);
    float d0 = 0.f;
#pragma unroll
    for (int j = 0; j < 8; ++j) d0 += qf[j] * kf0[j];
    d0 += __shfl_xor(d0, 1);
    d0 += __shfl_xor(d0, 2);
    d0 += __shfl_xor(d0, 4);
    float logit = d0 * 0.125f;
    float mn = fmaxf(m, logit);
    float sc = __expf(m - mn), p = __expf(logit - mn);
    ssum = ssum * sc + p;
#pragma unroll
    for (int j = 0; j < 8; ++j) a[j] = a[j] * sc + p * vf0[j];
    m = mn;
  }
  float inv = (e1 > e0) ? 1.f / (ssum + 1e-16f) : 0.f;
  float4* sp = (float4*)(s + (size_t)node * 512);
  float4 s0 = sp[l * 2], s1 = sp[l * 2 + 1];
  s0.x += a[0] * inv; s0.y += a[1] * inv; s0.z += a[2] * inv; s0.w += a[3] * inv;
  s1.x += a[4] * inv; s1.y += a[5] * inv; s1.z += a[6] * inv; s1.w += a[7] * inv;
  sp[l * 2] = s0;
  sp[l * 2 + 1] = s1;
}

// ---------------- BatchNorm ----------------
__global__ void k_bnstat(const float* __restrict__ s, float* __restrict__ acc) {
  int c = blockIdx.x * 256 + threadIdx.x;
  float sum = 0.f, sq = 0.f;
  for (int r = blockIdx.y; r < NN; r += 64) {
    float x = s[(size_t)r * 512 + c];
    sum += x;
    sq += x * x;
  }
  atomicAdd(&acc[c], sum);
  atomicAdd(&acc[512 + c], sq);
}

// BN(stats inline)+ReLU -> next-layer fp16 activations
__global__ void k_bnapply(const float* __restrict__ s, const float* __restrict__ bnacc,
                          const float* __restrict__ gamma, const float* __restrict__ beta,
                          u16* __restrict__ hh) {
  __shared__ float sscl[512], sshf[512];
  int tid = threadIdx.x;
#pragma unroll
  for (int c = tid; c < 512; c += 256) {
    float mu = bnacc[c] * (1.f / NN);
    float var = bnacc[512 + c] * (1.f / NN) - mu * mu;
    float inv = rsqrtf(var + 1e-5f);
    float scl = gamma[c] * inv;
    sscl[c] = scl;
    sshf[c] = beta[c] - mu * scl;
  }
  __syncthreads();
  int i = blockIdx.x * 256 + tid;  // 4-elem group
  float4 val = ((const float4*)s)[i];
  int c0 = (i & 127) * 4;
  float4 r;
  r.x = fmaxf(val.x * sscl[c0] + sshf[c0], 0.f);
  r.y = fmaxf(val.y * sscl[c0 + 1] + sshf[c0 + 1], 0.f);
  r.z = fmaxf(val.z * sscl[c0 + 2] + sshf[c0 + 2], 0.f);
  r.w = fmaxf(val.w * sscl[c0 + 3] + sshf[c0 + 3], 0.f);
  u16x4 h;
  h.x = f2h(r.x); h.y = f2h(r.y); h.z = f2h(r.z); h.w = f2h(r.w);
  ((u16x4*)hh)[i] = h;
}

// pool with BN(stats inline)+ReLU on the fly
__global__ void k_pool(const float* __restrict__ s, const float* __restrict__ bnacc,
                       const float* __restrict__ gamma, const float* __restrict__ beta,
                       const int* __restrict__ bstart, float* __restrict__ out, int layer) {
  int c = blockIdx.x * 256 + threadIdx.x;
  int b = blockIdx.y;
  float mu = bnacc[c] * (1.f / NN);
  float var = bnacc[512 + c] * (1.f / NN) - mu * mu;
  float inv = rsqrtf(var + 1e-5f);
  float scl = gamma[c] * inv;
  float shf = beta[c] - mu * scl;
  int r0 = bstart[b], r1 = bstart[b + 1];
  float sum = 0.f;
  for (int r = r0; r < r1; ++r)
    sum += fmaxf(s[(size_t)r * 512 + c] * scl + shf, 0.f);
  out[b * 4096 + layer * 512 + c] = sum / fmaxf((float)(r1 - r0), 1.f);
}

// ---------------- host ----------------
extern "C" void kernel_launch(void* const* d_in, const int* in_sizes, int n_in,
                              void* d_out, int out_size, void* d_ws, size_t ws_size,
                              hipStream_t stream) {
  (void)in_sizes; (void)n_in; (void)out_size; (void)ws_size;
  const float* x = (const float*)d_in[0];
  const int* ei = (const int*)d_in[1];
  const int* src = ei;
  const int* dst = ei + EE;
  const int* batch = (const int*)d_in[2];
  const float* W0q = (const float*)d_in[3];
  const float* b0q = (const float*)d_in[4];
  const float* W0k = (const float*)d_in[5];
  const float* b0k = (const float*)d_in[6];
  const float* W0v = (const float*)d_in[7];
  const float* b0v = (const float*)d_in[8];
  const float* W0s = (const float*)d_in[9];
  const float* b0s = (const float*)d_in[10];
  const float* Wq = (const float*)d_in[11];
  const float* bq = (const float*)d_in[12];
  const float* Wk = (const float*)d_in[13];
  const float* bk = (const float*)d_in[14];
  const float* Wv = (const float*)d_in[15];
  const float* bv = (const float*)d_in[16];
  const float* Ws = (const float*)d_in[17];
  const float* bs = (const float*)d_in[18];
  const float* gamma = (const float*)d_in[19];
  const float* beta = (const float*)d_in[20];
  float* out = (float*)d_out;

  char* w = (char*)d_ws;
  size_t off = 0;
  auto alloc = [&](size_t bytes) -> void* {
    void* p = w + off;
    off = (off + bytes + 255) & ~(size_t)255;
    return p;
  };
  u16* xh = (u16*)alloc((size_t)NN * FF * 2);
  u16* hh = (u16*)alloc((size_t)ND * 2);
  float* qb = (float*)alloc((size_t)ND * 4);
  u16* kb16 = (u16*)alloc((size_t)ND * 2);
  u16* vb16 = (u16*)alloc((size_t)ND * 2);
  float* sb = (float*)alloc((size_t)ND * 4);
  u16* wt0 = (u16*)alloc((size_t)4 * 512 * FF * 2);
  u16* wtN = (u16*)alloc((size_t)7 * 4 * 512 * 512 * 2);
  float* biasf = (float*)alloc((size_t)LL * 2048 * 4);
  float* bnacc = (float*)alloc(1024 * 4);
  int* counts = (int*)alloc(NN * 4);
  int* offs = (int*)alloc((NN + 1) * 4);
  int* cursor = (int*)alloc(NN * 4);
  int* esrc = (int*)alloc(EE * 4);
  int* bstart = (int*)alloc((BB + 1) * 4);

  // ---- once-per-launch setup ----
  hipMemsetAsync(counts, 0, NN * 4, stream);
  hipMemsetAsync(cursor, 0, NN * 4, stream);
  k_count<<<EE / 256, 256, 0, stream>>>(dst, counts);
  k_scan<<<1, 1024, 0, stream>>>(counts, offs);
  k_scatter<<<EE / 256, 256, 0, stream>>>(src, dst, offs, cursor, esrc);
  k_bstart<<<(NN + 256) / 256, 256, 0, stream>>>(batch, bstart);
  k_toh<<<(NN * FF / 4) / 256, 256, 0, stream>>>(x, xh, NN * FF / 4);
  k_convw<<<dim3(16, FF / 32, 4), dim3(32, 8), 0, stream>>>(W0q, W0k, W0v, W0s, FF, wt0);
  k_convw<<<dim3(16, 16, 28), dim3(32, 8), 0, stream>>>(Wq, Wk, Wv, Ws, DD, wtN);
  k_fbias<<<64, 256, 0, stream>>>(b0q, b0k, b0v, b0s, bq, bk, bv, bs, biasf);

  for (int layer = 0; layer < LL; ++layer) {
    int K = (layer == 0) ? FF : DD;
    const u16* A = (layer == 0) ? xh : hh;
    const u16* Bm = (layer == 0) ? wt0 : wtN + (size_t)(layer - 1) * 2048 * 512;
    k_gemm<<<dim3(16, 79), 256, 0, stream>>>(A, Bm, biasf + layer * 2048,
                                             qb, kb16, vb16, sb, NN, K);
    k_attn<<<NN / 4, 256, 0, stream>>>(qb, kb16, vb16, sb, offs, esrc);
    hipMemsetAsync(bnacc, 0, 1024 * 4, stream);
    k_bnstat<<<dim3(2, 64), 256, 0, stream>>>(sb, bnacc);
    k_bnapply<<<(ND / 4) / 256, 256, 0, stream>>>(sb, bnacc, gamma + layer * DD,
                                                  beta + layer * DD, hh);
    k_pool<<<dim3(2, 64), 256, 0, stream>>>(sb, bnacc, gamma + layer * DD,
                                            beta + layer * DD, bstart, out, layer);
  }
}